// Round 8
// baseline (136.124 us; speedup 1.0000x reference)
//
#include <hip/hip_runtime.h>
#include <math.h>

#define NB 8192
#define DK 256
#define STRIPS 32                   // 256-row block strips
#define UNITS 4224                  // sum over strips of (256 - 8*T) 32-col units
#define GRID 512                    // persistent blocks, 2/CU

typedef __bf16 bf16x8 __attribute__((ext_vector_type(8)));
typedef float f32x4 __attribute__((ext_vector_type(4)));

__device__ inline unsigned short f2bf(float f) {
  unsigned u = __float_as_uint(f);
  u += 0x7fffu + ((u >> 16) & 1u);          // round-to-nearest-even
  return (unsigned short)(u >> 16);
}

// ---------------- Kernel 1: L2-normalize rows, fp32 -> bf16
__global__ __launch_bounds__(256) void normalize_kernel(
    const float* __restrict__ emb, unsigned short* __restrict__ ebf) {
  int wave = threadIdx.x >> 6;
  int lane = threadIdx.x & 63;
  int row = blockIdx.x * 4 + wave;                  // one wave per row
  const float4* src = reinterpret_cast<const float4*>(emb + (size_t)row * DK) + lane;
  float4 v = *src;
  float ss = v.x * v.x + v.y * v.y + v.z * v.z + v.w * v.w;
  #pragma unroll
  for (int m = 1; m < 64; m <<= 1) ss += __shfl_xor(ss, m, 64);
  float inv = 1.0f / sqrtf(ss);
  ushort4 o;
  o.x = f2bf(v.x * inv);
  o.y = f2bf(v.y * inv);
  o.z = f2bf(v.z * inv);
  o.w = f2bf(v.w * inv);
  *reinterpret_cast<ushort4*>(ebf + (size_t)row * DK + lane * 4) = o;
}

// ---------------- Kernel 2: traffic-minimal GEMM, A-panel PINNED in VGPRs.
// R7 structure (verified absmax 0.0) + asm liveness pin: R7's VGPR_Count=132
// proved the compiler rematerialized the A loads per unit (540 MB L2 traffic).
// The empty asm with "+v" outputs makes the fragments opaque -> must be held.
__global__ __launch_bounds__(256, 1) void circle_gemm(
    const unsigned short* __restrict__ ebf, const int* __restrict__ labels,
    float* __restrict__ partial) {
  __shared__ float wsum[4];

  int b = blockIdx.x;
  int bid = (b & 7) * (GRID / 8) + (b >> 3);        // XCD swizzle (512 = 8*64)
  int u0 = (bid * UNITS) / GRID;
  int u1 = ((bid + 1) * UNITS) / GRID;

  int tid = threadIdx.x;
  int lane = tid & 63;
  int wave = tid >> 6;
  int frow = lane & 15;
  int fhi = lane >> 4;

  // decode first unit -> (strip T, col-tile c)
  int T = 0, cum = 0;
  while (u0 >= cum + (256 - 8 * T)) { cum += 256 - 8 * T; ++T; }
  int c = 8 * T + (u0 - cum);

  bf16x8 a[4][8];                                   // 64 rows x K=256: 128 VGPR
  int4 labRv[4];

  auto loadA = [&]() {
    int rbase = T * 256 + wave * 64;
    #pragma unroll
    for (int m = 0; m < 4; ++m) {
      const unsigned short* arow =
          ebf + (size_t)(rbase + 16 * m + frow) * DK + fhi * 8;
      #pragma unroll
      for (int ks = 0; ks < 8; ++ks)
        a[m][ks] = *reinterpret_cast<const bf16x8*>(arow + ks * 32);
      labRv[m] = *reinterpret_cast<const int4*>(
          &labels[rbase + 16 * m + fhi * 4]);
    }
    // liveness pin: force materialization NOW, forbid rematerialization later
    #pragma unroll
    for (int m = 0; m < 4; ++m)
      asm volatile("" : "+v"(a[m][0]), "+v"(a[m][1]), "+v"(a[m][2]),
                         "+v"(a[m][3]), "+v"(a[m][4]), "+v"(a[m][5]),
                         "+v"(a[m][6]), "+v"(a[m][7]));
  };
  loadA();

  float lsum = 0.0f;

  for (int u = u0; u < u1; ++u) {
    __builtin_amdgcn_s_barrier();                   // corral waves for L1 reuse
    int col0 = c * 32;
    int row0w = T * 256 + wave * 64;
    if (col0 + 32 > row0w) {                        // any weight > 0 here?
      bool full = (col0 >= row0w + 64);             // strictly above diagonal
      int labC[2];
      #pragma unroll
      for (int n = 0; n < 2; ++n) labC[n] = labels[col0 + 16 * n + frow];

      f32x4 acc[4][2] = {};
      #pragma unroll
      for (int ks = 0; ks < 8; ++ks) {
        bf16x8 bf0 = *reinterpret_cast<const bf16x8*>(
            ebf + (size_t)(col0 + frow) * DK + ks * 32 + fhi * 8);
        bf16x8 bf1 = *reinterpret_cast<const bf16x8*>(
            ebf + (size_t)(col0 + 16 + frow) * DK + ks * 32 + fhi * 8);
        #pragma unroll
        for (int m = 0; m < 4; ++m) {
          acc[m][0] = __builtin_amdgcn_mfma_f32_16x16x32_bf16(
              a[m][ks], bf0, acc[m][0], 0, 0, 0);
          acc[m][1] = __builtin_amdgcn_mfma_f32_16x16x32_bf16(
              a[m][ks], bf1, acc[m][1], 0, 0, 0);
        }
      }

      // epilogue; C/D layout (verified): col = lane&15, row = (lane>>4)*4+reg
      float usum = 0.0f;
      #pragma unroll
      for (int m = 0; m < 4; ++m) {
        #pragma unroll
        for (int n = 0; n < 2; ++n) {
          int gc = col0 + 16 * n + frow;
          #pragma unroll
          for (int e = 0; e < 4; ++e) {
            float sv = acc[m][n][e];
            int lr = ((const int*)&labRv[m])[e];
            bool pos = (lr == labC[n]);
            float relu = pos ? fmaxf(sv - 0.75f, 0.0f) : fmaxf(0.25f - sv, 0.0f);
            float arg  = pos ? (2.5f - 2.0f * sv)      : (2.0f * sv + 0.5f);
            float wf;
            if (full) {
              wf = 2.0f;
            } else {
              int gr = row0w + 16 * m + fhi * 4 + e;
              wf = (gc > gr) ? 2.0f : (gc == gr ? 1.0f : 0.0f);
            }
            usum += wf * relu * __expf(arg);
          }
        }
      }
      lsum += usum;
    }
    // advance to next unit; strip crossing reloads the A-panel
    ++c;
    if (c == 256 && u + 1 < u1) { ++T; c = 8 * T; loadA(); }
  }

  #pragma unroll
  for (int m = 32; m; m >>= 1) lsum += __shfl_xor(lsum, m, 64);
  if (lane == 0) wsum[wave] = lsum;
  __syncthreads();
  if (tid == 0) partial[bid] = wsum[0] + wsum[1] + wsum[2] + wsum[3];
}

// ---------------- Kernel 3: reduce partials + log1p (one block)
__global__ __launch_bounds__(256) void finalize_kernel(
    const float* __restrict__ partial, float* __restrict__ out) {
  __shared__ float wsum[4];
  int tid = threadIdx.x;
  float s = partial[tid] + partial[tid + 256];      // GRID = 512
  #pragma unroll
  for (int m = 32; m; m >>= 1) s += __shfl_xor(s, m, 64);
  if ((tid & 63) == 0) wsum[tid >> 6] = s;
  __syncthreads();
  if (tid == 0) out[0] = logf(1.0f + wsum[0] + wsum[1] + wsum[2] + wsum[3]);
}

extern "C" void kernel_launch(void* const* d_in, const int* in_sizes, int n_in,
                              void* d_out, int out_size, void* d_ws, size_t ws_size,
                              hipStream_t stream) {
  const float* emb = (const float*)d_in[0];
  const int* labels = (const int*)d_in[1];
  float* out = (float*)d_out;
  unsigned short* ebf = (unsigned short*)d_ws;                       // 4 MB bf16 E
  float* partial = (float*)((char*)d_ws + (size_t)NB * DK * 2);      // GRID floats

  hipLaunchKernelGGL(normalize_kernel, dim3(NB / 4), dim3(256), 0, stream, emb, ebf);
  hipLaunchKernelGGL(circle_gemm, dim3(GRID), dim3(256), 0, stream, ebf, labels, partial);
  hipLaunchKernelGGL(finalize_kernel, dim3(1), dim3(256), 0, stream, partial, out);
}

// Round 9
// 114.484 us; speedup vs baseline: 1.1890x; 1.1890x over previous
//
#include <hip/hip_runtime.h>
#include <math.h>

#define NB 8192
#define DK 256
#define BM 128
#define NTILE 64                    // NB/BM
#define NBLK (NTILE*(NTILE+1)/2)    // 2080 upper-triangular tiles

typedef __bf16 bf16x8 __attribute__((ext_vector_type(8)));
typedef float f32x4 __attribute__((ext_vector_type(4)));

__device__ inline unsigned short f2bf(float f) {
  unsigned u = __float_as_uint(f);
  u += 0x7fffu + ((u >> 16) & 1u);          // round-to-nearest-even
  return (unsigned short)(u >> 16);
}

__device__ inline void gld_lds16(const void* g, void* l) {
  __builtin_amdgcn_global_load_lds(
      (const __attribute__((address_space(1))) void*)g,
      (__attribute__((address_space(3))) void*)l, 16, 0, 0);
}

// ---------------- Kernel 1: L2-normalize rows, fp32 -> bf16
__global__ __launch_bounds__(256) void normalize_kernel(
    const float* __restrict__ emb, unsigned short* __restrict__ ebf) {
  int wave = threadIdx.x >> 6;
  int lane = threadIdx.x & 63;
  int row = blockIdx.x * 4 + wave;                  // one wave per row
  const float4* src = reinterpret_cast<const float4*>(emb + (size_t)row * DK) + lane;
  float4 v = *src;
  float ss = v.x * v.x + v.y * v.y + v.z * v.z + v.w * v.w;
  #pragma unroll
  for (int m = 1; m < 64; m <<= 1) ss += __shfl_xor(ss, m, 64);
  float inv = 1.0f / sqrtf(ss);
  ushort4 o;
  o.x = f2bf(v.x * inv);
  o.y = f2bf(v.y * inv);
  o.z = f2bf(v.z * inv);
  o.w = f2bf(v.w * inv);
  *reinterpret_cast<ushort4*>(ebf + (size_t)row * DK + lane * 4) = o;
}

// ---------------- Kernel 2: hybrid-delivery GEMM.
// Per 128x128 tile: B-panel (full K=256) staged ONCE into LDS (64 KB ->
// 2 blocks/CU co-resident; partner block hides stage drains); A-fragments
// stream directly from L1/L2 (XCD swizzle keeps the A-panel L2-hot across
// consecutive bids). ONE __syncthreads per block; unrolled k-loop lets
// waves drift and self-pipeline. LDS layout = R3's measured-zero-conflict
// form: 4 slabs of [128 rows][64 k] with the (row&7)<<4 XOR swizzle pair.
__global__ __launch_bounds__(256, 2) void circle_gemm(
    const unsigned short* __restrict__ ebf, const int* __restrict__ labels,
    float* __restrict__ partial) {
  __shared__ unsigned short Bs[4][BM * 64];          // 4 x 16 KB
  __shared__ float wsum[4];

  int b = blockIdx.x;
  int bid = (b & 7) * (NBLK / 8) + (b >> 3);         // XCD swizzle (2080%8==0)

  int rem = bid, tr = 0;                             // triangular decode
  while (rem >= NTILE - tr) { rem -= NTILE - tr; ++tr; }
  int tc = tr + rem;
  int row0 = tr * BM, col0 = tc * BM;

  int tid = threadIdx.x;
  int lane = tid & 63;
  int wave = tid >> 6;
  int wr = (wave >> 1) * 64;                         // wave's 64x64 sub-tile
  int wc = (wave & 1) * 64;
  int frow = lane & 15;
  int hi = lane >> 4;

  // stage full B panel: dest linear, source pre-swizzled (R3-verified pair)
  #pragma unroll
  for (int q = 0; q < 16; ++q) {
    int o = q * 4096 + tid * 16;                     // 0..65535 linear byte
    int s = o >> 14;                                 // slab (64-k block)
    int r = (o >> 7) & 127;                          // row within slab
    int os = o ^ ((r & 7) << 4);                     // swizzled (same row)
    int kc = ((os & 127) >> 1) + s * 64;             // bf16 col 0..255
    gld_lds16(&ebf[(size_t)(col0 + r) * DK + kc], ((char*)Bs) + o);
  }

  // labels straight to registers (L2-hot broadcast loads)
  int4 labRv[4];
  int labC[4];
  #pragma unroll
  for (int m = 0; m < 4; ++m)
    labRv[m] = *reinterpret_cast<const int4*>(
        &labels[row0 + wr + m * 16 + hi * 4]);
  #pragma unroll
  for (int n = 0; n < 4; ++n)
    labC[n] = labels[col0 + wc + n * 16 + frow];

  __syncthreads();                                   // the ONLY barrier

  f32x4 acc[4][4] = {};
  #pragma unroll
  for (int ks = 0; ks < 8; ++ks) {                   // K = 8 x 32
    int s = ks >> 1;
    int kk = (ks & 1) * 32 + hi * 8;                 // k within slab (bf16)
    bf16x8 av[4], bv[4];
    #pragma unroll
    for (int m = 0; m < 4; ++m)                      // A direct from L1/L2
      av[m] = *reinterpret_cast<const bf16x8*>(
          ebf + (size_t)(row0 + wr + m * 16 + frow) * DK + ks * 32 + hi * 8);
    #pragma unroll
    for (int n = 0; n < 4; ++n) {                    // B from LDS, swizzled
      int r = wc + n * 16 + frow;
      int ob = ((s << 14) + (r << 7) + kk * 2) ^ ((r & 7) << 4);
      bv[n] = *reinterpret_cast<const bf16x8*>(((const char*)Bs) + ob);
    }
    #pragma unroll
    for (int m = 0; m < 4; ++m)
      #pragma unroll
      for (int n = 0; n < 4; ++n)
        acc[m][n] = __builtin_amdgcn_mfma_f32_16x16x32_bf16(
            av[m], bv[n], acc[m][n], 0, 0, 0);
  }

  // epilogue; C/D layout (verified m89/m91): col=lane&15, row=(lane>>4)*4+reg
  float lsum = 0.0f;
  #pragma unroll
  for (int m = 0; m < 4; ++m) {
    #pragma unroll
    for (int n = 0; n < 4; ++n) {
      int lc = labC[n];
      #pragma unroll
      for (int e = 0; e < 4; ++e) {
        float sv = acc[m][n][e];
        int lr = ((const int*)&labRv[m])[e];
        bool pos = (lr == lc);
        float relu = pos ? fmaxf(sv - 0.75f, 0.0f) : fmaxf(0.25f - sv, 0.0f);
        float arg  = pos ? (2.5f - 2.0f * sv)      : (2.0f * sv + 0.5f);
        lsum += relu * __expf(arg);
      }
    }
  }
  #pragma unroll
  for (int m2 = 32; m2; m2 >>= 1) lsum += __shfl_xor(lsum, m2, 64);
  if (lane == 0) wsum[wave] = lsum;
  __syncthreads();
  if (tid == 0) {
    float s2 = wsum[0] + wsum[1] + wsum[2] + wsum[3];
    if (tc != tr) s2 *= 2.0f;                        // symmetry doubling
    partial[bid] = s2;
  }
}

// ---------------- Kernel 3: reduce partials + log1p (one block)
__global__ __launch_bounds__(256) void finalize_kernel(
    const float* __restrict__ partial, float* __restrict__ out) {
  __shared__ float wsum[4];
  int tid = threadIdx.x;
  float s = 0.0f;
  for (int i = tid; i < NBLK; i += 256) s += partial[i];
  #pragma unroll
  for (int m = 32; m; m >>= 1) s += __shfl_xor(s, m, 64);
  if ((tid & 63) == 0) wsum[tid >> 6] = s;
  __syncthreads();
  if (tid == 0) out[0] = logf(1.0f + wsum[0] + wsum[1] + wsum[2] + wsum[3]);
}

extern "C" void kernel_launch(void* const* d_in, const int* in_sizes, int n_in,
                              void* d_out, int out_size, void* d_ws, size_t ws_size,
                              hipStream_t stream) {
  const float* emb = (const float*)d_in[0];
  const int* labels = (const int*)d_in[1];
  float* out = (float*)d_out;
  unsigned short* ebf = (unsigned short*)d_ws;                       // 4 MB bf16 E
  float* partial = (float*)((char*)d_ws + (size_t)NB * DK * 2);      // 2080 floats

  hipLaunchKernelGGL(normalize_kernel, dim3(NB / 4), dim3(256), 0, stream, emb, ebf);
  hipLaunchKernelGGL(circle_gemm, dim3(NBLK), dim3(256), 0, stream, ebf, labels, partial);
  hipLaunchKernelGGL(finalize_kernel, dim3(1), dim3(256), 0, stream, partial, out);
}